// Round 5
// baseline (654.721 us; speedup 1.0000x reference)
//
#include <hip/hip_runtime.h>
#include <hip/hip_bf16.h>
#include <hip/hip_fp16.h>
#include <math.h>

// ---------------------------------------------------------------------------
// GCN 3-layer + mean-pool + linear head + softmax, fp32 in/out.
// CSR by dest (self-loops inlined, bare source-index meta). Norm folded:
//   out[c] = relu( dinv[c] * sum_{r in N(c)+self} (dinv[r]*xw[r]) + b )
// xw' = (x@W)*dinv stored fp16 (128B/row). GEMM: W column slice held in 16
// NAMED float4 registers (no arrays -> no scratch), 4 rows/iter for ILP,
// x broadcast via __shfl with literal lane indices (v_readlane).
// ---------------------------------------------------------------------------

#define F 64
#define NGRAPHS 128
#define NCLASSES 10
#define FCAT 192
#define SPLIT 8
#define SCAN_CHUNK 512
#define GEMM_BLOCKS 1024

// ---- preprocessing -------------------------------------------------------

__global__ void k_zero_int(int* __restrict__ p, int n) {
    int i = blockIdx.x * blockDim.x + threadIdx.x;
    if (i < n) p[i] = 0;
}
__global__ void k_zero_f(float* __restrict__ p, int n) {
    int i = blockIdx.x * blockDim.x + threadIdx.x;
    if (i < n) p[i] = 0.0f;
}

// slot[e] = position of edge e within its destination's segment
__global__ void k_count(const int* __restrict__ col, int* __restrict__ cnt,
                        int* __restrict__ slot, int E) {
    int e = blockIdx.x * blockDim.x + threadIdx.x;
    if (e < E) slot[e] = atomicAdd(&cnt[col[e]], 1);
}

// block sums of (cnt[i]+1) over chunks of 512
__global__ __launch_bounds__(256) void k_scan_block(const int* __restrict__ cnt, int n,
                                                    int* __restrict__ bsums) {
    __shared__ int red[256];
    int t = threadIdx.x;
    int base = blockIdx.x * SCAN_CHUNK;
    int i0 = base + 2 * t, i1 = i0 + 1;
    int v0 = (i0 < n) ? cnt[i0] + 1 : 0;
    int v1 = (i1 < n) ? cnt[i1] + 1 : 0;
    red[t] = v0 + v1;
    __syncthreads();
    for (int s = 128; s > 0; s >>= 1) {
        if (t < s) red[t] += red[t + s];
        __syncthreads();
    }
    if (t == 0) bsums[blockIdx.x] = red[0];
}

// serial exclusive scan of block sums (tiny)
__global__ void k_scan_sums(int* __restrict__ bsums, int nb, int* __restrict__ rowptr, int n) {
    if (threadIdx.x == 0 && blockIdx.x == 0) {
        int acc = 0;
        for (int b = 0; b < nb; ++b) { int v = bsums[b]; bsums[b] = acc; acc += v; }
        rowptr[n] = acc;
    }
}

// local exclusive scan + block base -> rowptr
__global__ __launch_bounds__(256) void k_scan_write(const int* __restrict__ cnt, int n,
                                                    const int* __restrict__ bsums,
                                                    int* __restrict__ rowptr) {
    __shared__ int sc[256];
    int t = threadIdx.x;
    int base = blockIdx.x * SCAN_CHUNK;
    int i0 = base + 2 * t, i1 = i0 + 1;
    int v0 = (i0 < n) ? cnt[i0] + 1 : 0;
    int v1 = (i1 < n) ? cnt[i1] + 1 : 0;
    int pair = v0 + v1;
    sc[t] = pair;
    __syncthreads();
    for (int off = 1; off < 256; off <<= 1) {
        int val = (t >= off) ? sc[t - off] : 0;
        __syncthreads();
        sc[t] += val;
        __syncthreads();
    }
    int excl = sc[t] - pair;
    int bs = bsums[blockIdx.x];
    if (i0 < n) rowptr[i0] = bs + excl;
    if (i1 < n) rowptr[i1] = bs + excl + v0;
}

// dinv = rsqrt(deg); self-loop CSR entry at slot 0
__global__ void k_self(const int* __restrict__ cnt, float* __restrict__ dinv,
                       const int* __restrict__ rowptr, int* __restrict__ metaIdx, int n) {
    int i = blockIdx.x * blockDim.x + threadIdx.x;
    if (i >= n) return;
    dinv[i] = rsqrtf((float)(cnt[i] + 1));
    metaIdx[rowptr[i]] = i;
}

// place each edge's source index at its precomputed CSR position (no atomics)
__global__ void k_fill(const int* __restrict__ row, const int* __restrict__ col,
                       const int* __restrict__ slot, const int* __restrict__ rowptr,
                       int* __restrict__ metaIdx, int E) {
    int e = blockIdx.x * blockDim.x + threadIdx.x;
    if (e >= E) return;
    metaIdx[rowptr[col[e]] + 1 + slot[e]] = row[e];
}

// ---- per-layer kernels ---------------------------------------------------

// xw'[r] = (x[r] @ W) * dinv[r], stored fp16.
// W column slice in 16 NAMED float4 registers; 4 rows per iteration.
__global__ __launch_bounds__(256) void k_gemm(const float* __restrict__ x,
                                              const float* __restrict__ W,
                                              const float* __restrict__ dinv,
                                              __half* __restrict__ xwh, int n) {
    const int lane = threadIdx.x & 63;
    const float* Wc = W + lane;
    float4 w0, w1, w2, w3, w4, w5, w6, w7, w8, w9, w10, w11, w12, w13, w14, w15;
#define LW(B) w##B = make_float4(Wc[(4*B+0)*F], Wc[(4*B+1)*F], Wc[(4*B+2)*F], Wc[(4*B+3)*F]);
    LW(0) LW(1) LW(2) LW(3) LW(4) LW(5) LW(6) LW(7)
    LW(8) LW(9) LW(10) LW(11) LW(12) LW(13) LW(14) LW(15)
#undef LW
    int wid = (int)((blockIdx.x * blockDim.x + threadIdx.x) >> 6);
    int nw  = (gridDim.x * blockDim.x) >> 6;
    int groups = (n + 3) >> 2;
    for (int g = wid; g < groups; g += nw) {
        int r0 = g * 4;
        int q1 = min(r0 + 1, n - 1), q2 = min(r0 + 2, n - 1), q3 = min(r0 + 3, n - 1);
        float xr0 = x[(size_t)r0 * F + lane];
        float xr1 = x[(size_t)q1 * F + lane];
        float xr2 = x[(size_t)q2 * F + lane];
        float xr3 = x[(size_t)q3 * F + lane];
        float a0 = 0.f, a1 = 0.f, a2 = 0.f, a3 = 0.f;
#define ST1(L, C) \
        a0 = fmaf(__shfl(xr0, (L)), C, a0); \
        a1 = fmaf(__shfl(xr1, (L)), C, a1); \
        a2 = fmaf(__shfl(xr2, (L)), C, a2); \
        a3 = fmaf(__shfl(xr3, (L)), C, a3);
#define ST(B) ST1(4*B+0, w##B.x) ST1(4*B+1, w##B.y) ST1(4*B+2, w##B.z) ST1(4*B+3, w##B.w)
        ST(0) ST(1) ST(2) ST(3) ST(4) ST(5) ST(6) ST(7)
        ST(8) ST(9) ST(10) ST(11) ST(12) ST(13) ST(14) ST(15)
#undef ST
#undef ST1
        __half* o = xwh + (size_t)r0 * F + lane;
        o[0] = __float2half(a0 * dinv[r0]);
        if (r0 + 1 < n) o[F]     = __float2half(a1 * dinv[q1]);
        if (r0 + 2 < n) o[2 * F] = __float2half(a2 * dinv[q2]);
        if (r0 + 3 < n) o[3 * F] = __float2half(a3 * dinv[q3]);
    }
}

// out[v] = relu( dinv[v] * sum_{r in CSR[v]} xw'[r] + b )
// one wave per node: 4 edge-groups x 16 lanes; each lane loads 4 halves (8B)
__global__ __launch_bounds__(256) void k_gather(const __half* __restrict__ xwh,
                                                const int* __restrict__ metaIdx,
                                                const int* __restrict__ rowptr,
                                                const float* __restrict__ dinv,
                                                const float* __restrict__ bias,
                                                float* __restrict__ out, int n) {
    int wid = (int)((blockIdx.x * blockDim.x + threadIdx.x) >> 6);
    if (wid >= n) return;
    int lane = threadIdx.x & 63;
    int g = lane >> 4, s = lane & 15;
    int start = rowptr[wid], end = rowptr[wid + 1];
    float ax = 0.0f, ay = 0.0f, az = 0.0f, aw = 0.0f;
    for (int i = start + g; i < end; i += 4) {
        int r = metaIdx[i];
        uint2 v = *((const uint2*)(xwh + ((size_t)r << 6)) + s);
        __half2 h0 = *reinterpret_cast<const __half2*>(&v.x);
        __half2 h1 = *reinterpret_cast<const __half2*>(&v.y);
        float2 f0 = __half22float2(h0);
        float2 f1 = __half22float2(h1);
        ax += f0.x; ay += f0.y; az += f1.x; aw += f1.y;
    }
#pragma unroll
    for (int m = 16; m <= 32; m <<= 1) {
        ax += __shfl_xor(ax, m);
        ay += __shfl_xor(ay, m);
        az += __shfl_xor(az, m);
        aw += __shfl_xor(aw, m);
    }
    if (g == 0) {
        float dc = dinv[wid];
        float4 bv = ((const float4*)bias)[s];
        float4 o;
        o.x = fmaxf(fmaf(ax, dc, bv.x), 0.0f);
        o.y = fmaxf(fmaf(ay, dc, bv.y), 0.0f);
        o.z = fmaxf(fmaf(az, dc, bv.z), 0.0f);
        o.w = fmaxf(fmaf(aw, dc, bv.w), 0.0f);
        *(float4*)(out + ((size_t)wid << 6) + (s << 2)) = o;
    }
}

// partial pooled sums: grid = NGRAPHS*SPLIT blocks, 256 threads
__global__ __launch_bounds__(256) void k_pool_part(const float* __restrict__ x,
                                                   const int* __restrict__ batch, int n,
                                                   float* __restrict__ pooledSum,
                                                   int layerOff) {
    int g = blockIdx.x / SPLIT, part = blockIdx.x % SPLIT;
    int lo = 0, hi = n;
    while (lo < hi) { int m = (lo + hi) >> 1; if (batch[m] < g) lo = m + 1; else hi = m; }
    int s0 = lo;
    lo = s0; hi = n;
    while (lo < hi) { int m = (lo + hi) >> 1; if (batch[m] < g + 1) lo = m + 1; else hi = m; }
    int e0 = lo;
    int len = e0 - s0;
    int chunk = (len + SPLIT - 1) / SPLIT;
    int r0 = s0 + part * chunk;
    int r1 = min(r0 + chunk, e0);
    int f = threadIdx.x & 63, sub = threadIdx.x >> 6;
    float sum = 0.0f;
    for (int i = r0 + sub; i < r1; i += 4) sum += x[(size_t)i * F + f];
    atomicAdd(&pooledSum[g * FCAT + layerOff + f], sum);
}

// logits = (pooledSum/cnt) @ Wf + bf ; softmax
__global__ void k_head(const float* __restrict__ pooledSum, const int* __restrict__ batch,
                       int n, const float* __restrict__ Wf, const float* __restrict__ bf,
                       float* __restrict__ out) {
    int g = blockIdx.x * blockDim.x + threadIdx.x;
    if (g >= NGRAPHS) return;
    int lo = 0, hi = n;
    while (lo < hi) { int m = (lo + hi) >> 1; if (batch[m] < g) lo = m + 1; else hi = m; }
    int s0 = lo;
    lo = s0; hi = n;
    while (lo < hi) { int m = (lo + hi) >> 1; if (batch[m] < g + 1) lo = m + 1; else hi = m; }
    float invc = 1.0f / fmaxf((float)(lo - s0), 1.0f);
    float logit[NCLASSES];
#pragma unroll
    for (int c = 0; c < NCLASSES; ++c) logit[c] = bf[c];
    for (int k = 0; k < FCAT; ++k) {
        float p = pooledSum[g * FCAT + k] * invc;
#pragma unroll
        for (int c = 0; c < NCLASSES; ++c) logit[c] = fmaf(p, Wf[k * NCLASSES + c], logit[c]);
    }
    float mx = logit[0];
#pragma unroll
    for (int c = 1; c < NCLASSES; ++c) mx = fmaxf(mx, logit[c]);
    float ssum = 0.0f;
#pragma unroll
    for (int c = 0; c < NCLASSES; ++c) { logit[c] = expf(logit[c] - mx); ssum += logit[c]; }
    float inv = 1.0f / ssum;
#pragma unroll
    for (int c = 0; c < NCLASSES; ++c) out[g * NCLASSES + c] = logit[c] * inv;
}

// ---------------------------------------------------------------------------

extern "C" void kernel_launch(void* const* d_in, const int* in_sizes, int n_in,
                              void* d_out, int out_size, void* d_ws, size_t ws_size,
                              hipStream_t stream) {
    const float* features = (const float*)d_in[0];
    const int*   edge     = (const int*)d_in[1];
    const int*   batch    = (const int*)d_in[2];
    const float* W1 = (const float*)d_in[3]; const float* b1 = (const float*)d_in[4];
    const float* W2 = (const float*)d_in[5]; const float* b2 = (const float*)d_in[6];
    const float* W3 = (const float*)d_in[7]; const float* b3 = (const float*)d_in[8];
    const float* Wf = (const float*)d_in[9]; const float* bf = (const float*)d_in[10];
    float* out = (float*)d_out;

    const int n = in_sizes[0] / F;   // 100000
    const int E = in_sizes[1] / 2;   // 1600000
    const int* row = edge;
    const int* col = edge + E;

    const int NB = (n + SCAN_CHUNK - 1) / SCAN_CHUNK;

    // workspace layout
    float*  bufA = (float*)d_ws;                       // [n*64]
    float*  bufB = bufA + (size_t)n * F;               // [n*64]
    __half* xwh  = (__half*)(bufB + (size_t)n * F);    // [n*64] fp16
    int*    metaIdx = (int*)(xwh + (size_t)n * F);     // [E+n]
    int*    cnt  = metaIdx + (size_t)E + n;            // [n]
    float*  dinv = (float*)(cnt + n);                  // [n]
    int*    rowptr = (int*)(dinv + n);                 // [n+1]
    int*    bsums  = rowptr + (n + 1);                 // [NB]
    float*  pooledSum = (float*)(bsums + NB);          // [128*192]
    int*    slot = (int*)bufA;                         // [E] aliases bufA (CSR phase only)

    const int BT = 256;
    int gn  = (n + BT - 1) / BT;
    int gE  = (E + BT - 1) / BT;
    int gW  = (n + 3) / 4;       // gather grid (4 nodes per block)

    // ---- CSR build ----
    k_zero_int<<<gn, BT, 0, stream>>>(cnt, n);
    k_zero_f<<<(NGRAPHS * FCAT + BT - 1) / BT, BT, 0, stream>>>(pooledSum, NGRAPHS * FCAT);
    k_count<<<gE, BT, 0, stream>>>(col, cnt, slot, E);
    k_scan_block<<<NB, BT, 0, stream>>>(cnt, n, bsums);
    k_scan_sums<<<1, 64, 0, stream>>>(bsums, NB, rowptr, n);
    k_scan_write<<<NB, BT, 0, stream>>>(cnt, n, bsums, rowptr);
    k_self<<<gn, BT, 0, stream>>>(cnt, dinv, rowptr, metaIdx, n);
    k_fill<<<gE, BT, 0, stream>>>(row, col, slot, rowptr, metaIdx, E);

    // ---- layer 1: features -> bufA ----
    k_gemm<<<GEMM_BLOCKS, BT, 0, stream>>>(features, W1, dinv, xwh, n);
    k_gather<<<gW, BT, 0, stream>>>(xwh, metaIdx, rowptr, dinv, b1, bufA, n);
    k_pool_part<<<NGRAPHS * SPLIT, BT, 0, stream>>>(bufA, batch, n, pooledSum, 0);

    // ---- layer 2: bufA -> bufB ----
    k_gemm<<<GEMM_BLOCKS, BT, 0, stream>>>(bufA, W2, dinv, xwh, n);
    k_gather<<<gW, BT, 0, stream>>>(xwh, metaIdx, rowptr, dinv, b2, bufB, n);
    k_pool_part<<<NGRAPHS * SPLIT, BT, 0, stream>>>(bufB, batch, n, pooledSum, F);

    // ---- layer 3: bufB -> bufA ----
    k_gemm<<<GEMM_BLOCKS, BT, 0, stream>>>(bufB, W3, dinv, xwh, n);
    k_gather<<<gW, BT, 0, stream>>>(xwh, metaIdx, rowptr, dinv, b3, bufA, n);
    k_pool_part<<<NGRAPHS * SPLIT, BT, 0, stream>>>(bufA, batch, n, pooledSum, 2 * F);

    // ---- head ----
    k_head<<<2, 64, 0, stream>>>(pooledSum, batch, n, Wf, bf, out);
}

// Round 6
// 427.253 us; speedup vs baseline: 1.5324x; 1.5324x over previous
//
#include <hip/hip_runtime.h>
#include <hip/hip_bf16.h>
#include <hip/hip_fp16.h>
#include <math.h>

// ---------------------------------------------------------------------------
// GCN 3-layer + mean-pool + linear head + softmax, fp32 in/out.
// CSR by dest (self-loops inlined, bare source-index meta). Norm folded:
//   out[c] = relu( dinv[c] * sum_{r in N(c)+self} (dinv[r]*xw[r]) + b )
// Feature pipeline is fp16 end-to-end: x (fp16) @ W (fp16, pre-transposed)
// via v_mfma_f32_16x16x32_f16 (fp32 accum), xw' = xw*dinv stored fp16,
// gather outputs fp16, pool accumulates fp32.
// ---------------------------------------------------------------------------

#define F 64
#define NGRAPHS 128
#define NCLASSES 10
#define FCAT 192
#define SPLIT 8
#define SCAN_CHUNK 512

typedef _Float16 f16x8 __attribute__((ext_vector_type(8)));
typedef float f32x4 __attribute__((ext_vector_type(4)));

// ---- preprocessing -------------------------------------------------------

__global__ void k_zero_int(int* __restrict__ p, int n) {
    int i = blockIdx.x * blockDim.x + threadIdx.x;
    if (i < n) p[i] = 0;
}
__global__ void k_zero_f(float* __restrict__ p, int n) {
    int i = blockIdx.x * blockDim.x + threadIdx.x;
    if (i < n) p[i] = 0.0f;
}

// slot[e] = position of edge e within its destination's segment
__global__ void k_count(const int* __restrict__ col, int* __restrict__ cnt,
                        int* __restrict__ slot, int E) {
    int e = blockIdx.x * blockDim.x + threadIdx.x;
    if (e < E) slot[e] = atomicAdd(&cnt[col[e]], 1);
}

// block sums of (cnt[i]+1) over chunks of 512
__global__ __launch_bounds__(256) void k_scan_block(const int* __restrict__ cnt, int n,
                                                    int* __restrict__ bsums) {
    __shared__ int red[256];
    int t = threadIdx.x;
    int base = blockIdx.x * SCAN_CHUNK;
    int i0 = base + 2 * t, i1 = i0 + 1;
    int v0 = (i0 < n) ? cnt[i0] + 1 : 0;
    int v1 = (i1 < n) ? cnt[i1] + 1 : 0;
    red[t] = v0 + v1;
    __syncthreads();
    for (int s = 128; s > 0; s >>= 1) {
        if (t < s) red[t] += red[t + s];
        __syncthreads();
    }
    if (t == 0) bsums[blockIdx.x] = red[0];
}

// serial exclusive scan of block sums (tiny)
__global__ void k_scan_sums(int* __restrict__ bsums, int nb, int* __restrict__ rowptr, int n) {
    if (threadIdx.x == 0 && blockIdx.x == 0) {
        int acc = 0;
        for (int b = 0; b < nb; ++b) { int v = bsums[b]; bsums[b] = acc; acc += v; }
        rowptr[n] = acc;
    }
}

// local exclusive scan + block base -> rowptr
__global__ __launch_bounds__(256) void k_scan_write(const int* __restrict__ cnt, int n,
                                                    const int* __restrict__ bsums,
                                                    int* __restrict__ rowptr) {
    __shared__ int sc[256];
    int t = threadIdx.x;
    int base = blockIdx.x * SCAN_CHUNK;
    int i0 = base + 2 * t, i1 = i0 + 1;
    int v0 = (i0 < n) ? cnt[i0] + 1 : 0;
    int v1 = (i1 < n) ? cnt[i1] + 1 : 0;
    int pair = v0 + v1;
    sc[t] = pair;
    __syncthreads();
    for (int off = 1; off < 256; off <<= 1) {
        int val = (t >= off) ? sc[t - off] : 0;
        __syncthreads();
        sc[t] += val;
        __syncthreads();
    }
    int excl = sc[t] - pair;
    int bs = bsums[blockIdx.x];
    if (i0 < n) rowptr[i0] = bs + excl;
    if (i1 < n) rowptr[i1] = bs + excl + v0;
}

// dinv = rsqrt(deg); self-loop CSR entry at slot 0
__global__ void k_self(const int* __restrict__ cnt, float* __restrict__ dinv,
                       const int* __restrict__ rowptr, int* __restrict__ metaIdx, int n) {
    int i = blockIdx.x * blockDim.x + threadIdx.x;
    if (i >= n) return;
    dinv[i] = rsqrtf((float)(cnt[i] + 1));
    metaIdx[rowptr[i]] = i;
}

// place each edge's source index at its precomputed CSR position (no atomics)
__global__ void k_fill(const int* __restrict__ row, const int* __restrict__ col,
                       const int* __restrict__ slot, const int* __restrict__ rowptr,
                       int* __restrict__ metaIdx, int E) {
    int e = blockIdx.x * blockDim.x + threadIdx.x;
    if (e >= E) return;
    metaIdx[rowptr[col[e]] + 1 + slot[e]] = row[e];
}

// features fp32 -> fp16
__global__ void k_cvt(const float* __restrict__ in, __half* __restrict__ out, int total4) {
    int i = blockIdx.x * blockDim.x + threadIdx.x;
    if (i >= total4) return;
    float4 v = *((const float4*)in + i);
    __half2 h0 = __floats2half2_rn(v.x, v.y);
    __half2 h1 = __floats2half2_rn(v.z, v.w);
    __half2* op = (__half2*)out + 2 * (size_t)i;
    op[0] = h0; op[1] = h1;
}

// W1,W2,W3 fp32 [k][c] -> Wt fp16 [w][c][k] (transposed, 3x64x64)
__global__ void k_wcvt(const float* __restrict__ W1, const float* __restrict__ W2,
                       const float* __restrict__ W3, __half* __restrict__ Wt) {
    int t = blockIdx.x * blockDim.x + threadIdx.x;
    if (t >= 3 * 4096) return;
    int w = t >> 12, idx = t & 4095;
    int c = idx >> 6, k = idx & 63;
    const float* W = (w == 0) ? W1 : (w == 1) ? W2 : W3;
    Wt[t] = __float2half(W[k * F + c]);
}

// ---- per-layer kernels ---------------------------------------------------

// xw'[r] = (x[r] @ W) * dinv[r], fp16 in, fp32 accum (MFMA), fp16 out.
// One wave per 16-row tile; Wt is [64 cols][64 k] fp16 (K-contiguous).
__global__ __launch_bounds__(256) void k_gemm(const __half* __restrict__ xh,
                                              const __half* __restrict__ Wt,
                                              const float* __restrict__ dinv,
                                              __half* __restrict__ xwh, int n) {
    int wid = (int)((blockIdx.x * blockDim.x + threadIdx.x) >> 6);
    int lane = threadIdx.x & 63;
    int r0 = wid * 16;
    if (r0 >= n) return;
    int rA = min(r0 + (lane & 15), n - 1);
    int kOff = (lane >> 4) * 8;
    const f16x8* ap = (const f16x8*)(xh + (size_t)rA * F + kOff);
    f16x8 a0 = ap[0];
    f16x8 a1 = ap[4];            // +32 halves
    f32x4 acc0, acc1, acc2, acc3;
#define DO_CT(CT, ACC) { \
        const f16x8* bp = (const f16x8*)(Wt + (((CT) * 16 + (lane & 15)) << 6) + kOff); \
        f16x8 b0 = bp[0], b1 = bp[4]; \
        f32x4 c = {0.f, 0.f, 0.f, 0.f}; \
        c = __builtin_amdgcn_mfma_f32_16x16x32_f16(a0, b0, c, 0, 0, 0); \
        c = __builtin_amdgcn_mfma_f32_16x16x32_f16(a1, b1, c, 0, 0, 0); \
        ACC = c; }
    DO_CT(0, acc0) DO_CT(1, acc1) DO_CT(2, acc2) DO_CT(3, acc3)
#undef DO_CT
    int rBase = r0 + ((lane >> 4) << 2);    // this lane's 4 output rows
    float d0 = dinv[min(rBase + 0, n - 1)];
    float d1 = dinv[min(rBase + 1, n - 1)];
    float d2 = dinv[min(rBase + 2, n - 1)];
    float d3 = dinv[min(rBase + 3, n - 1)];
    int cl = lane & 15;
#define ST_CT(CT, ACC) { \
        __half* op = xwh + (size_t)rBase * F + (CT) * 16 + cl; \
        if (rBase + 0 < n) op[0 * F] = __float2half(ACC.x * d0); \
        if (rBase + 1 < n) op[1 * F] = __float2half(ACC.y * d1); \
        if (rBase + 2 < n) op[2 * F] = __float2half(ACC.z * d2); \
        if (rBase + 3 < n) op[3 * F] = __float2half(ACC.w * d3); }
    ST_CT(0, acc0) ST_CT(1, acc1) ST_CT(2, acc2) ST_CT(3, acc3)
#undef ST_CT
}

// out[v] = relu( dinv[v] * sum_{r in CSR[v]} xw'[r] + b ), fp16 out
// one wave per node: 4 edge-groups x 16 lanes; each lane loads 4 halves (8B)
__global__ __launch_bounds__(256) void k_gather(const __half* __restrict__ xwh,
                                                const int* __restrict__ metaIdx,
                                                const int* __restrict__ rowptr,
                                                const float* __restrict__ dinv,
                                                const float* __restrict__ bias,
                                                __half* __restrict__ out, int n) {
    int wid = (int)((blockIdx.x * blockDim.x + threadIdx.x) >> 6);
    if (wid >= n) return;
    int lane = threadIdx.x & 63;
    int g = lane >> 4, s = lane & 15;
    int start = rowptr[wid], end = rowptr[wid + 1];
    float ax = 0.0f, ay = 0.0f, az = 0.0f, aw = 0.0f;
    for (int i = start + g; i < end; i += 4) {
        int r = metaIdx[i];
        uint2 v = *((const uint2*)(xwh + ((size_t)r << 6)) + s);
        __half2 h0 = *reinterpret_cast<const __half2*>(&v.x);
        __half2 h1 = *reinterpret_cast<const __half2*>(&v.y);
        float2 f0 = __half22float2(h0);
        float2 f1 = __half22float2(h1);
        ax += f0.x; ay += f0.y; az += f1.x; aw += f1.y;
    }
#pragma unroll
    for (int m = 16; m <= 32; m <<= 1) {
        ax += __shfl_xor(ax, m);
        ay += __shfl_xor(ay, m);
        az += __shfl_xor(az, m);
        aw += __shfl_xor(aw, m);
    }
    if (g == 0) {
        float dc = dinv[wid];
        float4 bv = ((const float4*)bias)[s];
        __half2 h0 = __floats2half2_rn(fmaxf(fmaf(ax, dc, bv.x), 0.0f),
                                       fmaxf(fmaf(ay, dc, bv.y), 0.0f));
        __half2 h1 = __floats2half2_rn(fmaxf(fmaf(az, dc, bv.z), 0.0f),
                                       fmaxf(fmaf(aw, dc, bv.w), 0.0f));
        __half2* op = (__half2*)(out + ((size_t)wid << 6) + (s << 2));
        op[0] = h0; op[1] = h1;
    }
}

// partial pooled sums: grid = NGRAPHS*SPLIT blocks, 256 threads, fp16 in
__global__ __launch_bounds__(256) void k_pool_part(const __half* __restrict__ x,
                                                   const int* __restrict__ batch, int n,
                                                   float* __restrict__ pooledSum,
                                                   int layerOff) {
    int g = blockIdx.x / SPLIT, part = blockIdx.x % SPLIT;
    int lo = 0, hi = n;
    while (lo < hi) { int m = (lo + hi) >> 1; if (batch[m] < g) lo = m + 1; else hi = m; }
    int s0 = lo;
    lo = s0; hi = n;
    while (lo < hi) { int m = (lo + hi) >> 1; if (batch[m] < g + 1) lo = m + 1; else hi = m; }
    int e0 = lo;
    int len = e0 - s0;
    int chunk = (len + SPLIT - 1) / SPLIT;
    int r0 = s0 + part * chunk;
    int r1 = min(r0 + chunk, e0);
    int f = threadIdx.x & 63, sub = threadIdx.x >> 6;
    float sum = 0.0f;
    for (int i = r0 + sub; i < r1; i += 4) sum += __half2float(x[(size_t)i * F + f]);
    atomicAdd(&pooledSum[g * FCAT + layerOff + f], sum);
}

// logits = (pooledSum/cnt) @ Wf + bf ; softmax
__global__ void k_head(const float* __restrict__ pooledSum, const int* __restrict__ batch,
                       int n, const float* __restrict__ Wf, const float* __restrict__ bf,
                       float* __restrict__ out) {
    int g = blockIdx.x * blockDim.x + threadIdx.x;
    if (g >= NGRAPHS) return;
    int lo = 0, hi = n;
    while (lo < hi) { int m = (lo + hi) >> 1; if (batch[m] < g) lo = m + 1; else hi = m; }
    int s0 = lo;
    lo = s0; hi = n;
    while (lo < hi) { int m = (lo + hi) >> 1; if (batch[m] < g + 1) lo = m + 1; else hi = m; }
    float invc = 1.0f / fmaxf((float)(lo - s0), 1.0f);
    float logit[NCLASSES];
#pragma unroll
    for (int c = 0; c < NCLASSES; ++c) logit[c] = bf[c];
    for (int k = 0; k < FCAT; ++k) {
        float p = pooledSum[g * FCAT + k] * invc;
#pragma unroll
        for (int c = 0; c < NCLASSES; ++c) logit[c] = fmaf(p, Wf[k * NCLASSES + c], logit[c]);
    }
    float mx = logit[0];
#pragma unroll
    for (int c = 1; c < NCLASSES; ++c) mx = fmaxf(mx, logit[c]);
    float ssum = 0.0f;
#pragma unroll
    for (int c = 0; c < NCLASSES; ++c) { logit[c] = expf(logit[c] - mx); ssum += logit[c]; }
    float inv = 1.0f / ssum;
#pragma unroll
    for (int c = 0; c < NCLASSES; ++c) out[g * NCLASSES + c] = logit[c] * inv;
}

// ---------------------------------------------------------------------------

extern "C" void kernel_launch(void* const* d_in, const int* in_sizes, int n_in,
                              void* d_out, int out_size, void* d_ws, size_t ws_size,
                              hipStream_t stream) {
    const float* features = (const float*)d_in[0];
    const int*   edge     = (const int*)d_in[1];
    const int*   batch    = (const int*)d_in[2];
    const float* W1 = (const float*)d_in[3]; const float* b1 = (const float*)d_in[4];
    const float* W2 = (const float*)d_in[5]; const float* b2 = (const float*)d_in[6];
    const float* W3 = (const float*)d_in[7]; const float* b3 = (const float*)d_in[8];
    const float* Wf = (const float*)d_in[9]; const float* bf = (const float*)d_in[10];
    float* out = (float*)d_out;

    const int n = in_sizes[0] / F;   // 100000
    const int E = in_sizes[1] / 2;   // 1600000
    const int* row = edge;
    const int* col = edge + E;

    const int NB = (n + SCAN_CHUNK - 1) / SCAN_CHUNK;

    // workspace layout (fp16 feature buffers)
    __half* x0h  = (__half*)d_ws;                      // [n*64]
    __half* bufAh = x0h + (size_t)n * F;               // [n*64]
    __half* bufBh = bufAh + (size_t)n * F;             // [n*64]
    __half* xwh  = bufBh + (size_t)n * F;              // [n*64]
    __half* Wt   = xwh + (size_t)n * F;                // [3*64*64]
    int*    metaIdx = (int*)(Wt + 3 * F * F);          // [E+n]
    int*    slot = metaIdx + (size_t)E + n;            // [E]
    int*    cnt  = slot + E;                           // [n]
    float*  dinv = (float*)(cnt + n);                  // [n]
    int*    rowptr = (int*)(dinv + n);                 // [n+1]
    int*    bsums  = rowptr + (n + 1);                 // [NB]
    float*  pooledSum = (float*)(bsums + NB);          // [128*192]

    const int BT = 256;
    int gn  = (n + BT - 1) / BT;
    int gE  = (E + BT - 1) / BT;
    int gW  = (n + 3) / 4;                 // gather grid (4 nodes/block)
    int gT  = ((n + 15) / 16 + 3) / 4;     // gemm grid (4 tiles/block)
    int gC  = ((n * F / 4) + BT - 1) / BT; // cvt grid

    // ---- CSR build + converts ----
    k_zero_int<<<gn, BT, 0, stream>>>(cnt, n);
    k_zero_f<<<(NGRAPHS * FCAT + BT - 1) / BT, BT, 0, stream>>>(pooledSum, NGRAPHS * FCAT);
    k_count<<<gE, BT, 0, stream>>>(col, cnt, slot, E);
    k_scan_block<<<NB, BT, 0, stream>>>(cnt, n, bsums);
    k_scan_sums<<<1, 64, 0, stream>>>(bsums, NB, rowptr, n);
    k_scan_write<<<NB, BT, 0, stream>>>(cnt, n, bsums, rowptr);
    k_self<<<gn, BT, 0, stream>>>(cnt, dinv, rowptr, metaIdx, n);
    k_fill<<<gE, BT, 0, stream>>>(row, col, slot, rowptr, metaIdx, E);
    k_wcvt<<<(3 * 4096 + BT - 1) / BT, BT, 0, stream>>>(W1, W2, W3, Wt);
    k_cvt<<<gC, BT, 0, stream>>>(features, x0h, n * F / 4);

    // ---- layer 1: x0h -> bufAh ----
    k_gemm<<<gT, BT, 0, stream>>>(x0h, Wt, dinv, xwh, n);
    k_gather<<<gW, BT, 0, stream>>>(xwh, metaIdx, rowptr, dinv, b1, bufAh, n);
    k_pool_part<<<NGRAPHS * SPLIT, BT, 0, stream>>>(bufAh, batch, n, pooledSum, 0);

    // ---- layer 2: bufAh -> bufBh ----
    k_gemm<<<gT, BT, 0, stream>>>(bufAh, Wt + 4096, dinv, xwh, n);
    k_gather<<<gW, BT, 0, stream>>>(xwh, metaIdx, rowptr, dinv, b2, bufBh, n);
    k_pool_part<<<NGRAPHS * SPLIT, BT, 0, stream>>>(bufBh, batch, n, pooledSum, F);

    // ---- layer 3: bufBh -> x0h (reuse) ----
    k_gemm<<<gT, BT, 0, stream>>>(bufBh, Wt + 8192, dinv, xwh, n);
    k_gather<<<gW, BT, 0, stream>>>(xwh, metaIdx, rowptr, dinv, b3, x0h, n);
    k_pool_part<<<NGRAPHS * SPLIT, BT, 0, stream>>>(x0h, batch, n, pooledSum, 2 * F);

    // ---- head ----
    k_head<<<2, 64, 0, stream>>>(pooledSum, batch, n, Wf, bf, out);
}